// Round 11
// baseline (191.072 us; speedup 1.0000x reference)
//
#include <hip/hip_runtime.h>

#define N_NODES 50000
#define N_EDGES 800000
#define IN_DIM 16
#define OUT_DIM 16
#define N_RELS 90
#define N_BASES 30

#define CAP 24            // bucket rows per node (avg deg 16; P(deg>24) ~ 2%)
#define LDS_USTRIDE 264   // bf16 elems per relation row (256 + 8 pad)
#define EDGES_PER_BLK 1600  // 500 blocks x 1600 = 800000 (2 blocks/CU)

#define PREP_BLOCKS 91   // 91*256 = 23296 >= 23088
#define DOTS_BLOCKS 196  // 196*256 = 50176 >= 50000
#define ZERO_BLOCKS 196
#define HZ_BLOCKS 782    // 782*256 float4 >= 200000 float4 (zero hout)

typedef unsigned int uint32;
typedef unsigned short ushort16;

__device__ __forceinline__ float4 shfl_xor4(float4 v, int m) {
    float4 r;
    r.x = __shfl_xor(v.x, m); r.y = __shfl_xor(v.y, m);
    r.z = __shfl_xor(v.z, m); r.w = __shfl_xor(v.w, m);
    return r;
}

__device__ __forceinline__ ushort16 f2bf(float f) {
    uint32 b = __float_as_uint(f);
    b = (b + 0x7FFFu + ((b >> 16) & 1u)) >> 16;   // round-to-nearest-even
    return (ushort16)b;
}
__device__ __forceinline__ float bflo(uint32 u) { return __uint_as_float(u << 16); }
__device__ __forceinline__ float bfhi(uint32 u) { return __uint_as_float(u & 0xffff0000u); }

// ---------------------------------------------------------------------------
// Setup: [0,91) prep Wrel(bf16)+avec; [91,287) node dots; [287,483) zero cnt;
// [483,1265) zero hout.
// ---------------------------------------------------------------------------
__global__ __launch_bounds__(256) void setup_kernel(
    const float* __restrict__ Ws,
    const float* __restrict__ Wa,
    const float* __restrict__ weight,
    const float* __restrict__ w_comp,
    const float* __restrict__ h,
    ushort16* __restrict__ Wrelh,      // [90*256] bf16
    float* __restrict__ avec,
    float2* __restrict__ s13,
    int* __restrict__ cnt,
    float* __restrict__ hout)
{
    int b = blockIdx.x;
    if (b < PREP_BLOCKS) {
        int f = b * 256 + threadIdx.x;
        if (f < N_RELS * IN_DIM * OUT_DIM) {
            int a   = f / (N_RELS * OUT_DIM);
            int rem = f % (N_RELS * OUT_DIM);
            int r   = rem / OUT_DIM;
            int o   = rem % OUT_DIM;
            float acc = 0.f;
            #pragma unroll
            for (int bb = 0; bb < N_BASES; ++bb)
                acc += w_comp[r * N_BASES + bb] * weight[a * (N_BASES * OUT_DIM) + bb * OUT_DIM + o];
            Wrelh[f] = f2bf(acc);
        } else if (f < N_RELS * IN_DIM * OUT_DIM + 48) {
            int g = f - N_RELS * IN_DIM * OUT_DIM;
            int k = g / IN_DIM;
            int i = g % IN_DIM;
            float acc = 0.f;
            #pragma unroll
            for (int o = 0; o < OUT_DIM; ++o)
                acc += Wa[k * OUT_DIM + o] * Ws[o * IN_DIM + i];
            avec[g] = acc;
        }
    } else if (b < PREP_BLOCKS + DOTS_BLOCKS) {
        __shared__ float la[48];
        if (threadIdx.x < 48) {
            int k = threadIdx.x / IN_DIM;
            int i = threadIdx.x % IN_DIM;
            float acc = 0.f;
            #pragma unroll
            for (int o = 0; o < OUT_DIM; ++o)
                acc += Wa[k * OUT_DIM + o] * Ws[o * IN_DIM + i];
            la[threadIdx.x] = acc;
        }
        __syncthreads();
        int n = (b - PREP_BLOCKS) * 256 + threadIdx.x;
        if (n >= N_NODES) return;
        const float4* p = (const float4*)(h + (size_t)n * IN_DIM);
        float d1 = 0.f, d3 = 0.f;
        #pragma unroll
        for (int i = 0; i < 4; ++i) {
            float4 v = p[i];
            d1 += v.x * la[4*i+0] + v.y * la[4*i+1] + v.z * la[4*i+2] + v.w * la[4*i+3];
            d3 += v.x * la[32+4*i+0] + v.y * la[32+4*i+1] + v.z * la[32+4*i+2] + v.w * la[32+4*i+3];
        }
        s13[n] = make_float2(d1, d3);
    } else if (b < PREP_BLOCKS + DOTS_BLOCKS + ZERO_BLOCKS) {
        int n = (b - PREP_BLOCKS - DOTS_BLOCKS) * 256 + threadIdx.x;
        if (n < N_NODES) cnt[n] = 0;
    } else {
        int idx = (b - PREP_BLOCKS - DOTS_BLOCKS - ZERO_BLOCKS) * 256 + threadIdx.x;
        if (idx < N_NODES * OUT_DIM / 4) {
            float4 z = {0.f, 0.f, 0.f, 0.f};
            ((float4*)hout)[idx] = z;
        }
    }
}

// ---------------------------------------------------------------------------
// Edge compute: bf16 Wrel in LDS (47.5KB -> 2 blocks/CU), 1024 threads,
// contiguous 1600-edge range, 4 lanes/edge, 4-edge batch (loads-then-process).
// bf16 bucket rows (32B); overflow -> f32 atomicAdd into pre-zeroed hout.
// ---------------------------------------------------------------------------
__global__ __launch_bounds__(1024) void compute_lds_kernel(
    const float* __restrict__ h,
    const float* __restrict__ he,
    const int* __restrict__ src,
    const int* __restrict__ dst,
    const int* __restrict__ rel,
    const ushort16* __restrict__ Wrelh,
    const float* __restrict__ avec,
    const float2* __restrict__ s13,
    int* __restrict__ cnt,
    ushort16* __restrict__ bucket,  // [N_NODES*CAP*16] bf16
    float* __restrict__ hout)       // overflow target (pre-zeroed)
{
    extern __shared__ uint32 lwu[];   // [N_RELS * LDS_USTRIDE/2] uints

    // ---- stage Wrel(bf16) -> LDS (padded row stride), uint-coalesced ----
    const uint32* Wu = (const uint32*)Wrelh;
    for (int j = threadIdx.x; j < N_RELS * 128; j += 1024) {
        int r = j >> 7;            // 128 uints per relation (256 bf16)
        int w = j & 127;
        lwu[r * (LDS_USTRIDE / 2) + w] = Wu[j];
    }
    __syncthreads();

    const int t = threadIdx.x;
    const int q = t & 3;
    const int grp = t >> 2;                 // 0..255
    const int lbase = (t & 63) & ~3;
    const int ebeg = blockIdx.x * EDGES_PER_BLK;
    const int eend = ebeg + EDGES_PER_BLK;

    float4 av = *(const float4*)(avec + 16 + 4 * q);

    for (int base = ebeg + grp; base < eend; base += 1024) {
        int e[4], s[4], d[4], r[4];
        bool val[4];

        // ---- [1] all idx loads ----
        #pragma unroll
        for (int k = 0; k < 4; ++k) {
            e[k] = base + k * 256;
            val[k] = (e[k] < eend);
            int ec = val[k] ? e[k] : ebeg;
            s[k] = src[ec]; d[k] = dst[ec]; r[k] = rel[ec];
        }

        // ---- [2] all data loads (independent gather chains) ----
        float4 heq[4], hq[4];
        float2 svs[4], svd[4];
        #pragma unroll
        for (int k = 0; k < 4; ++k) {
            int ec = val[k] ? e[k] : ebeg;
            heq[k] = *(const float4*)(he + (size_t)ec * IN_DIM + q * 4);
            hq[k]  = *(const float4*)(h  + (size_t)s[k] * IN_DIM + q * 4);
            svs[k] = s13[s[k]];
            svd[k] = s13[d[k]];
        }

        // ---- [3] all slot atomics ----
        int slot[4];
        #pragma unroll
        for (int k = 0; k < 4; ++k) {
            slot[k] = 0;
            if (q == 0 && val[k]) slot[k] = atomicAdd(&cnt[d[k]], 1);
        }

        // ---- [4] process ----
        #pragma unroll
        for (int k = 0; k < 4; ++k) {
            if (!val[k]) continue;
            int sl = __shfl(slot[k], lbase);

            float pd = heq[k].x * av.x + heq[k].y * av.y + heq[k].z * av.z + heq[k].w * av.w;
            pd += __shfl_xor(pd, 1);
            pd += __shfl_xor(pd, 2);
            float score = svs[k].x + svd[k].y + pd;

            float4 o1 = shfl_xor4(hq[k], 1);
            float4 o2 = shfl_xor4(hq[k], 2);
            float4 o3 = shfl_xor4(o1, 2);
            bool q0 = (q == 0), q1 = (q == 1), q2 = (q == 2);
            float4 row0 = q0 ? hq[k] : q1 ? o1 : q2 ? o2 : o3;
            float4 row1 = q0 ? o1 : q1 ? hq[k] : q2 ? o3 : o2;
            float4 row2 = q0 ? o2 : q1 ? o3 : q2 ? hq[k] : o1;
            float4 row3 = q0 ? o3 : q1 ? o2 : q2 ? o1 : hq[k];
            float hs[16] = {row0.x,row0.y,row0.z,row0.w, row1.x,row1.y,row1.z,row1.w,
                            row2.x,row2.y,row2.z,row2.w, row3.x,row3.y,row3.z,row3.w};

            // matvec from bf16 LDS: lane reads uint2 (4 bf16) per i
            const uint32* wb = lwu + (size_t)r[k] * (LDS_USTRIDE / 2) + q * 2;
            float4 acc = {0.f, 0.f, 0.f, 0.f};
            #pragma unroll
            for (int i = 0; i < 16; ++i) {
                uint32 u0 = wb[i * 8 + 0];
                uint32 u1 = wb[i * 8 + 1];
                float hv = hs[i];
                acc.x += hv * bflo(u0); acc.y += hv * bfhi(u0);
                acc.z += hv * bflo(u1); acc.w += hv * bfhi(u1);
            }
            acc.x *= score; acc.y *= score; acc.z *= score; acc.w *= score;

            if (sl < CAP) {
                // bf16 row: lane q writes 4 bf16 = 8B, 4 lanes -> 32B row
                uint32 p0 = ((uint32)f2bf(acc.y) << 16) | (uint32)f2bf(acc.x);
                uint32 p1 = ((uint32)f2bf(acc.w) << 16) | (uint32)f2bf(acc.z);
                uint2 pkt = make_uint2(p0, p1);
                *(uint2*)((ushort16*)bucket + ((size_t)d[k] * CAP + sl) * OUT_DIM + q * 4) = pkt;
            } else {
                float* outp = hout + (size_t)d[k] * OUT_DIM + q * 4;
                atomicAdd(outp + 0, acc.x);
                atomicAdd(outp + 1, acc.y);
                atomicAdd(outp + 2, acc.z);
                atomicAdd(outp + 3, acc.w);
            }
        }
    }
}

// ---------------------------------------------------------------------------
// Reduce: 16 lanes/node (quarter q x 4 j-streams), bf16 rows, f32 accumulate,
// 2-step butterfly; plain store for deg<=CAP, atomicAdd for deg>CAP.
// ---------------------------------------------------------------------------
__global__ __launch_bounds__(256) void reduce_bucket_kernel(
    const ushort16* __restrict__ bucket,
    const int* __restrict__ cnt,
    float* __restrict__ hout)
{
    int tid = blockIdx.x * 256 + threadIdx.x;
    int n = tid >> 4;
    int l = tid & 15;
    int q = l & 3;
    int p = l >> 2;
    if (n >= N_NODES) return;

    int deg = cnt[n];
    int m = deg > CAP ? CAP : deg;
    float4 acc = {0.f, 0.f, 0.f, 0.f};
    for (int j = p; j < m; j += 4) {
        const uint2 v = *(const uint2*)(bucket + ((size_t)n * CAP + j) * OUT_DIM + q * 4);
        acc.x += bflo(v.x); acc.y += bfhi(v.x);
        acc.z += bflo(v.y); acc.w += bfhi(v.y);
    }
    acc.x += __shfl_xor(acc.x, 4); acc.y += __shfl_xor(acc.y, 4);
    acc.z += __shfl_xor(acc.z, 4); acc.w += __shfl_xor(acc.w, 4);
    acc.x += __shfl_xor(acc.x, 8); acc.y += __shfl_xor(acc.y, 8);
    acc.z += __shfl_xor(acc.z, 8); acc.w += __shfl_xor(acc.w, 8);

    if (p == 0) {
        if (deg <= CAP) {
            *(float4*)(hout + (size_t)n * OUT_DIM + q * 4) = acc;
        } else {
            float* outp = hout + (size_t)n * OUT_DIM + q * 4;
            atomicAdd(outp + 0, acc.x);
            atomicAdd(outp + 1, acc.y);
            atomicAdd(outp + 2, acc.z);
            atomicAdd(outp + 3, acc.w);
        }
    }
}

// ===========================================================================
// Fallback (ws too small): f32 direct atomic scatter (known-correct).
// ===========================================================================
__global__ __launch_bounds__(256) void prep_kernel(
    const float* __restrict__ Ws, const float* __restrict__ Wa,
    const float* __restrict__ weight, const float* __restrict__ w_comp,
    float* __restrict__ Wrel, float* __restrict__ avec)
{
    int f = blockIdx.x * blockDim.x + threadIdx.x;
    if (f < N_RELS * IN_DIM * OUT_DIM) {
        int a   = f / (N_RELS * OUT_DIM);
        int rem = f % (N_RELS * OUT_DIM);
        int r   = rem / OUT_DIM;
        int o   = rem % OUT_DIM;
        float acc = 0.f;
        #pragma unroll
        for (int b = 0; b < N_BASES; ++b)
            acc += w_comp[r * N_BASES + b] * weight[a * (N_BASES * OUT_DIM) + b * OUT_DIM + o];
        Wrel[f] = acc;
    } else if (f < N_RELS * IN_DIM * OUT_DIM + 48) {
        int g = f - N_RELS * IN_DIM * OUT_DIM;
        int k = g / IN_DIM;
        int i = g % IN_DIM;
        float acc = 0.f;
        #pragma unroll
        for (int o = 0; o < OUT_DIM; ++o)
            acc += Wa[k * OUT_DIM + o] * Ws[o * IN_DIM + i];
        avec[g] = acc;
    }
}

__global__ __launch_bounds__(256) void edge_atomic_kernel(
    const float* __restrict__ h,
    const float* __restrict__ he,
    const int* __restrict__ src,
    const int* __restrict__ dst,
    const int* __restrict__ rel,
    const float* __restrict__ Wrel,
    const float* __restrict__ avec,
    float* __restrict__ hout)
{
    int e = blockIdx.x * blockDim.x + threadIdx.x;
    if (e >= N_EDGES) return;
    int s = src[e], d = dst[e], r = rel[e];
    float hs[IN_DIM];
    const float4* p = (const float4*)(h + (size_t)s * IN_DIM);
    #pragma unroll
    for (int i = 0; i < 4; ++i) {
        float4 v = p[i];
        hs[4*i+0] = v.x; hs[4*i+1] = v.y; hs[4*i+2] = v.z; hs[4*i+3] = v.w;
    }
    float score = 0.f;
    #pragma unroll
    for (int i = 0; i < IN_DIM; ++i) score += hs[i] * avec[i];
    const float4* qe = (const float4*)(he + (size_t)e * IN_DIM);
    #pragma unroll
    for (int i = 0; i < 4; ++i) {
        float4 v = qe[i];
        score += v.x * avec[16+4*i] + v.y * avec[17+4*i] + v.z * avec[18+4*i] + v.w * avec[19+4*i];
    }
    const float4* pd = (const float4*)(h + (size_t)d * IN_DIM);
    #pragma unroll
    for (int i = 0; i < 4; ++i) {
        float4 v = pd[i];
        score += v.x * avec[32+4*i] + v.y * avec[33+4*i] + v.z * avec[34+4*i] + v.w * avec[35+4*i];
    }
    float acc[OUT_DIM];
    #pragma unroll
    for (int o = 0; o < OUT_DIM; ++o) acc[o] = 0.f;
    const float* W = Wrel + (size_t)r * 256;
    #pragma unroll
    for (int i = 0; i < IN_DIM; ++i) {
        float hv = hs[i];
        #pragma unroll
        for (int o = 0; o < OUT_DIM; ++o) acc[o] += hv * W[i * OUT_DIM + o];
    }
    float* outp = hout + (size_t)d * OUT_DIM;
    #pragma unroll
    for (int o = 0; o < OUT_DIM; ++o) atomicAdd(outp + o, acc[o] * score);
}

extern "C" void kernel_launch(void* const* d_in, const int* in_sizes, int n_in,
                              void* d_out, int out_size, void* d_ws, size_t ws_size,
                              hipStream_t stream) {
    const float* h      = (const float*)d_in[0];
    const float* he     = (const float*)d_in[1];
    const float* Ws     = (const float*)d_in[2];
    const float* Wa     = (const float*)d_in[3];
    const float* weight = (const float*)d_in[4];
    const float* w_comp = (const float*)d_in[5];
    const int*   src    = (const int*)d_in[6];
    const int*   dst    = (const int*)d_in[7];
    const int*   rel    = (const int*)d_in[8];
    float* hout = (float*)d_out;

    // ws layout (float units)
    const size_t OFF_WRELH  = 0;         // 23040 bf16 = 11520 f
    const size_t OFF_AVEC   = 11520;     // 48 f (+16 pad)
    const size_t OFF_S13    = 11584;     // 100000 f
    const size_t OFF_CNT    = 111584;    // 50000 i
    const size_t OFF_BUCKET = 161584;    // N*CAP*16 bf16 = 9,600,000 f
    const size_t NEED_BUCKET = (OFF_BUCKET + (size_t)N_NODES * CAP * OUT_DIM / 2) * 4;

    float* wsf  = (float*)d_ws;
    ushort16* Wrelh = (ushort16*)(wsf + OFF_WRELH);
    float* avec = wsf + OFF_AVEC;
    float2* s13 = (float2*)(wsf + OFF_S13);
    int* cnt    = (int*)(wsf + OFF_CNT);

    if (ws_size >= NEED_BUCKET) {
        ushort16* bucket = (ushort16*)(wsf + OFF_BUCKET);

        setup_kernel<<<PREP_BLOCKS + DOTS_BLOCKS + ZERO_BLOCKS + HZ_BLOCKS, 256, 0, stream>>>(
            Ws, Wa, weight, w_comp, h, Wrelh, avec, s13, cnt, hout);
        compute_lds_kernel<<<N_EDGES / EDGES_PER_BLK, 1024,
                             N_RELS * (LDS_USTRIDE / 2) * sizeof(uint32), stream>>>(
            h, he, src, dst, rel, Wrelh, avec, s13, cnt, bucket, hout);
        reduce_bucket_kernel<<<(N_NODES * 16 + 255) / 256, 256, 0, stream>>>(
            bucket, cnt, hout);
    } else {
        hipMemsetAsync(d_out, 0, (size_t)out_size * sizeof(float), stream);
        float* Wrel = wsf;  // f32 layout for fallback
        float* avf  = wsf + 23040;
        int total = N_RELS * IN_DIM * OUT_DIM + 48;
        prep_kernel<<<(total + 255) / 256, 256, 0, stream>>>(Ws, Wa, weight, w_comp, Wrel, avf);
        edge_atomic_kernel<<<(N_EDGES + 255) / 256, 256, 0, stream>>>(
            h, he, src, dst, rel, Wrel, avf, hout);
    }
}